// Round 11
// baseline (352.886 us; speedup 1.0000x reference)
//
#include <hip/hip_runtime.h>
#include <hip/hip_bf16.h>

// Problem constants (from reference): NU=NI=50000, DF=128, DL=64, E=1.2e6
constexpr int kNU = 50000;
constexpr int kDF = 128;
constexpr int kDL = 64;
constexpr int kBShift = 4;             // 16 dst rows per bucket
constexpr int kBCap   = 384;           // slots/bucket (mean 192, sigma~14 -> 13 sigma)
constexpr int kOvfCap = 4096;

__device__ __forceinline__ float bf16hi_to_f(unsigned int u) {
    return __uint_as_float(u);
}

// ---------------------------------------------------------------------------
// xw_kernel: [MLP (rows >= NU) | preference] -> L2 normalize -> @W_conv
//            -> bf16 xw table.  (round-8 proven structure)
// ---------------------------------------------------------------------------
__global__ __launch_bounds__(256) void xw_kernel(
    const float* __restrict__ features,    // [NI, 128]
    const float* __restrict__ preference,  // [NU, 64]
    const float* __restrict__ W_mlp,       // [64, 128] row-major
    const float* __restrict__ b_mlp,       // [64]
    const float* __restrict__ W_conv,      // [64, 64] row-major
    __hip_bfloat16* __restrict__ xwb,      // [n, 64] bf16
    int n_total)
{
    __shared__ float Wt[kDF * 65];         // Wt[k*65+l] = W_mlp[l][k]
    __shared__ float Wc[kDL * kDL];
    __shared__ float bs[kDL];
    __shared__ float frow[4][2][kDF];
    __shared__ float xls[4][2][kDL];

    const int tid = threadIdx.x;
    for (int idx = tid; idx < kDL * kDF; idx += 256) {
        int k = idx & (kDF - 1);
        int l = idx >> 7;
        Wt[k * 65 + l] = W_mlp[idx];
    }
    for (int idx = tid; idx < kDL * kDL; idx += 256) Wc[idx] = W_conv[idx];
    if (tid < kDL) bs[tid] = b_mlp[tid];
    __syncthreads();

    const int lane   = tid & 63;
    const int wid    = tid >> 6;
    const int wglob  = blockIdx.x * 4 + wid;
    const int nwaves = gridDim.x * 4;
    const int npairs = n_total >> 1;

    for (int pr = wglob; pr < npairs; pr += nwaves) {
        const int rA = 2 * pr, rB = rA + 1;
        float vA, vB;
        if (rA < kNU) {
            vA = preference[(size_t)rA * kDL + lane];
            vB = preference[(size_t)rB * kDL + lane];
        } else {
            const float* fA = features + (size_t)(rA - kNU) * kDF;
            const float* fB = fA + kDF;
            frow[wid][0][lane]      = fA[lane];
            frow[wid][0][lane + 64] = fA[lane + 64];
            frow[wid][1][lane]      = fB[lane];
            frow[wid][1][lane + 64] = fB[lane + 64];
            float a0 = bs[lane], a1 = 0.f, a2 = 0.f, a3 = 0.f;
            float c0 = bs[lane], c1 = 0.f, c2 = 0.f, c3 = 0.f;
            #pragma unroll
            for (int k = 0; k < kDF; k += 4) {
                const float4 fa = *reinterpret_cast<const float4*>(&frow[wid][0][k]);
                const float4 fb = *reinterpret_cast<const float4*>(&frow[wid][1][k]);
                const float w0 = Wt[(k)     * 65 + lane];
                const float w1 = Wt[(k + 1) * 65 + lane];
                const float w2 = Wt[(k + 2) * 65 + lane];
                const float w3 = Wt[(k + 3) * 65 + lane];
                a0 = fmaf(fa.x, w0, a0);  c0 = fmaf(fb.x, w0, c0);
                a1 = fmaf(fa.y, w1, a1);  c1 = fmaf(fb.y, w1, c1);
                a2 = fmaf(fa.z, w2, a2);  c2 = fmaf(fb.z, w2, c2);
                a3 = fmaf(fa.w, w3, a3);  c3 = fmaf(fb.w, w3, c3);
            }
            vA = (a0 + a1) + (a2 + a3);
            vB = (c0 + c1) + (c2 + c3);
        }
        float sA = vA * vA, sB = vB * vB;
        #pragma unroll
        for (int o = 32; o > 0; o >>= 1) {
            sA += __shfl_xor(sA, o);
            sB += __shfl_xor(sB, o);
        }
        const float xlA = vA / fmaxf(sqrtf(sA), 1e-12f);
        const float xlB = vB / fmaxf(sqrtf(sB), 1e-12f);
        xls[wid][0][lane] = xlA;
        xls[wid][1][lane] = xlB;

        float pA0 = 0.f, pA1 = 0.f, pA2 = 0.f, pA3 = 0.f;
        float pB0 = 0.f, pB1 = 0.f, pB2 = 0.f, pB3 = 0.f;
        #pragma unroll
        for (int l = 0; l < kDL; l += 4) {
            const float4 xA = *reinterpret_cast<const float4*>(&xls[wid][0][l]);
            const float4 xB = *reinterpret_cast<const float4*>(&xls[wid][1][l]);
            const float w0 = Wc[(l)     * kDL + lane];
            const float w1 = Wc[(l + 1) * kDL + lane];
            const float w2 = Wc[(l + 2) * kDL + lane];
            const float w3 = Wc[(l + 3) * kDL + lane];
            pA0 = fmaf(xA.x, w0, pA0);  pB0 = fmaf(xB.x, w0, pB0);
            pA1 = fmaf(xA.y, w1, pA1);  pB1 = fmaf(xB.y, w1, pB1);
            pA2 = fmaf(xA.z, w2, pA2);  pB2 = fmaf(xB.z, w2, pB2);
            pA3 = fmaf(xA.w, w3, pA3);  pB3 = fmaf(xB.w, w3, pB3);
        }
        xwb[(size_t)rA * kDL + lane] = __float2bfloat16((pA0 + pA1) + (pA2 + pA3));
        xwb[(size_t)rB * kDL + lane] = __float2bfloat16((pB0 + pB1) + (pB2 + pB3));
    }
}

// ---------------------------------------------------------------------------
// binhist: fused [per-dst histogram | dst-bucket binning].  Packed entry
// (src<<4)|(dst&15) fits 21 bits.  Bucket-sequential staging -> hot tail
// lines stay cached -> ~1x write amplification.  Exact overflow fallback.
// ---------------------------------------------------------------------------
__global__ __launch_bounds__(256) void binhist_kernel(
    const int* __restrict__ src, const int* __restrict__ dst,
    int* __restrict__ deg, int* __restrict__ cur,
    int* __restrict__ bucket, int* __restrict__ ovfcnt, int2* __restrict__ ovf,
    int nE)
{
    int i = (blockIdx.x * 256 + threadIdx.x) * 4;
    if (i + 3 < nE) {
        const int4 s4 = *reinterpret_cast<const int4*>(src + i);
        const int4 d4 = *reinterpret_cast<const int4*>(dst + i);
        const int ss[4] = {s4.x, s4.y, s4.z, s4.w};
        const int dd[4] = {d4.x, d4.y, d4.z, d4.w};
        #pragma unroll
        for (int j = 0; j < 4; ++j) {
            const int s = ss[j], d = dd[j];
            atomicAdd(&deg[d], 1);
            const int b = d >> kBShift;
            const int p = atomicAdd(&cur[b], 1);
            if (p < kBCap) {
                bucket[b * kBCap + p] = (s << 4) | (d & 15);
            } else {
                const int q = atomicAdd(ovfcnt, 1);
                if (q < kOvfCap) ovf[q] = make_int2(s, d);
            }
        }
    } else {
        for (; i < nE; ++i) {
            const int s = src[i], d = dst[i];
            atomicAdd(&deg[d], 1);
            const int b = d >> kBShift;
            const int p = atomicAdd(&cur[b], 1);
            if (p < kBCap) {
                bucket[b * kBCap + p] = (s << 4) | (d & 15);
            } else {
                const int q = atomicAdd(ovfcnt, 1);
                if (q < kOvfCap) ovf[q] = make_int2(s, d);
            }
        }
    }
}

// ---------------------------------------------------------------------------
// scan_part / scan_apply (round-8 proven)
// ---------------------------------------------------------------------------
__global__ __launch_bounds__(256) void scan_part(
    const int* __restrict__ deg, int* __restrict__ off,
    int* __restrict__ part, int n)
{
    __shared__ int wsum[4];
    const int tid = threadIdx.x, lane = tid & 63, w = tid >> 6;
    const int i0 = (blockIdx.x * 256 + tid) * 4;
    int4 v = make_int4(0, 0, 0, 0);
    if (i0 + 3 < n) {
        v = *reinterpret_cast<const int4*>(deg + i0);
    } else {
        if (i0     < n) v.x = deg[i0];
        if (i0 + 1 < n) v.y = deg[i0 + 1];
        if (i0 + 2 < n) v.z = deg[i0 + 2];
    }
    const int t = v.x + v.y + v.z + v.w;
    int s = t;
    #pragma unroll
    for (int d = 1; d < 64; d <<= 1) {
        int u = __shfl_up(s, d);
        if (lane >= d) s += u;
    }
    if (lane == 63) wsum[w] = s;
    __syncthreads();
    int wexcl = 0;
    if (w > 0) wexcl += wsum[0];
    if (w > 1) wexcl += wsum[1];
    if (w > 2) wexcl += wsum[2];
    const int pfx = wexcl + (s - t);
    if (i0     < n) off[i0]     = pfx;
    if (i0 + 1 < n) off[i0 + 1] = pfx + v.x;
    if (i0 + 2 < n) off[i0 + 2] = pfx + v.x + v.y;
    if (i0 + 3 < n) off[i0 + 3] = pfx + v.x + v.y + v.z;
    if (tid == 0) part[blockIdx.x] = wsum[0] + wsum[1] + wsum[2] + wsum[3];
}

__global__ __launch_bounds__(256) void scan_apply(
    const int* __restrict__ part, int* __restrict__ off, int n)
{
    const int b = blockIdx.x;
    if (b == 0) return;
    const int tid = threadIdx.x, lane = tid & 63;
    int pv = (lane < b) ? part[lane] : 0;
    if (lane + 64 < b) pv += part[lane + 64];
    #pragma unroll
    for (int o = 32; o > 0; o >>= 1) pv += __shfl_xor(pv, o);
    const int i0 = (b * 256 + tid) * 4;
    if (i0 + 3 < n) {
        int4 v = *reinterpret_cast<int4*>(off + i0);
        v.x += pv; v.y += pv; v.z += pv; v.w += pv;
        *reinterpret_cast<int4*>(off + i0) = v;
    } else {
        if (i0     < n) off[i0]     += pv;
        if (i0 + 1 < n) off[i0 + 1] += pv;
        if (i0 + 2 < n) off[i0 + 2] += pv;
    }
}

// ---------------------------------------------------------------------------
// bfill: one block per bucket; coalesced bucket read; csr writes confined to
// the bucket's contiguous csr span.  Post-fill off[r] = END of row r.
// ---------------------------------------------------------------------------
__global__ __launch_bounds__(256) void bfill_kernel(
    const int* __restrict__ cur, const int* __restrict__ bucket,
    int* __restrict__ off, int* __restrict__ csr)
{
    const int b = blockIdx.x;
    const int n = min(cur[b], kBCap);
    const int base_d = b << kBShift;
    for (int t = threadIdx.x; t < n; t += 256) {
        const int pk = bucket[b * kBCap + t];
        const int d = base_d | (pk & 15);
        const int s = pk >> 4;
        const int p = atomicAdd(&off[d], 1);
        csr[p] = s;
    }
}

// overflow cleanup (expected count 0; exact fallback)
__global__ __launch_bounds__(256) void ovf_kernel(
    const int* __restrict__ ovfcnt, const int2* __restrict__ ovf,
    int* __restrict__ off, int* __restrict__ csr)
{
    const int n = min(ovfcnt[0], kOvfCap);
    for (int t = blockIdx.x * 256 + threadIdx.x; t < n; t += 256 * gridDim.x) {
        const int2 e = ovf[t];
        const int p = atomicAdd(&off[e.y], 1);
        csr[p] = e.x;
    }
}

// ---------------------------------------------------------------------------
// gather (round-8 proven): one wave per dst row; 8 groups x 8 lanes; CSR row
// preloaded coalesced + shfl redistribute; bf16 rows as uint4; fused leaky.
// ---------------------------------------------------------------------------
__global__ __launch_bounds__(256) void gather_kernel(
    const uint4* __restrict__ xwb4,
    const int* __restrict__ off,           // post-fill: end offsets
    const int* __restrict__ csr,
    float4* __restrict__ out4, int n)
{
    const int r = blockIdx.x * 4 + (threadIdx.x >> 6);
    if (r >= n) return;
    const int lane = threadIdx.x & 63;
    const int g = lane >> 3;
    const int c = lane & 7;
    const int e0  = r ? off[r - 1] : 0;
    const int deg = off[r] - e0;

    const int s_all = (lane < deg) ? csr[e0 + lane] : 0;

    float acc[8];
    #pragma unroll
    for (int j = 0; j < 8; ++j) acc[j] = 0.f;

    for (int base = 0; base < deg; base += 8) {
        const int idx = base + g;
        int s = (idx < 64) ? __shfl(s_all, idx)
                           : ((idx < deg) ? csr[e0 + idx] : 0);
        if (idx < deg) {
            const uint4 v = xwb4[(size_t)s * 8 + c];
            acc[0] += bf16hi_to_f(v.x << 16);
            acc[1] += bf16hi_to_f(v.x & 0xffff0000u);
            acc[2] += bf16hi_to_f(v.y << 16);
            acc[3] += bf16hi_to_f(v.y & 0xffff0000u);
            acc[4] += bf16hi_to_f(v.z << 16);
            acc[5] += bf16hi_to_f(v.z & 0xffff0000u);
            acc[6] += bf16hi_to_f(v.w << 16);
            acc[7] += bf16hi_to_f(v.w & 0xffff0000u);
        }
    }
    #pragma unroll
    for (int j = 0; j < 8; ++j) {
        acc[j] += __shfl_xor(acc[j], 8);
        acc[j] += __shfl_xor(acc[j], 16);
        acc[j] += __shfl_xor(acc[j], 32);
    }
    if (g == 0) {
        #pragma unroll
        for (int j = 0; j < 8; ++j)
            acc[j] = acc[j] >= 0.f ? acc[j] : 0.01f * acc[j];
        const float4 o0 = make_float4(acc[0], acc[1], acc[2], acc[3]);
        const float4 o1 = make_float4(acc[4], acc[5], acc[6], acc[7]);
        out4[(size_t)r * 16 + c * 2]     = o0;
        out4[(size_t)r * 16 + c * 2 + 1] = o1;
    }
}

extern "C" void kernel_launch(void* const* d_in, const int* in_sizes, int n_in,
                              void* d_out, int out_size, void* d_ws, size_t ws_size,
                              hipStream_t stream) {
    // inputs: 0=id_embedding (UNUSED), 1=features, 2=preference,
    //         3=W_mlp, 4=b_mlp, 5=W_conv, 6=edge_index
    const float* features   = (const float*)d_in[1];
    const float* preference = (const float*)d_in[2];
    const float* W_mlp      = (const float*)d_in[3];
    const float* b_mlp      = (const float*)d_in[4];
    const float* W_conv     = (const float*)d_in[5];
    const int*   edge_index = (const int*)d_in[6];

    const int nE      = in_sizes[6] / 2;           // 1,200,000
    const int n_total = out_size / kDL;            // 100,000
    const int nb      = (n_total + 15) >> kBShift; // 6250 buckets

    // ws layout (16B-aligned segments), ~28.1 MB total:
    //   xwb    : n_total*64 bf16          = 12,800,000 B
    //   off    : (n_total+4) int          =    400,016 B
    //   [deg | cur(+pad) | ovfcnt] memset =    425,024 B
    //   part   : 128 int                  =        512 B
    //   ovf    : kOvfCap int2             =     32,768 B
    //   bucket : nb*kBCap int             =  9,600,000 B
    //   csr    : nE int                   =  4,800,000 B
    char* wp = (char*)d_ws;
    __hip_bfloat16* xwb = (__hip_bfloat16*)wp;  wp += (size_t)n_total * kDL * 2;
    int* off    = (int*)wp;                     wp += (size_t)(n_total + 4) * 4;
    int* deg    = (int*)wp;                     wp += (size_t)n_total * 4;
    int* cur    = (int*)wp;                     wp += (size_t)6252 * 4;   // nb + pad
    int* ovfcnt = (int*)wp;                     wp += 16;
    int* part   = (int*)wp;                     wp += 512;
    int2* ovf   = (int2*)wp;                    wp += (size_t)kOvfCap * 8;
    int* bucket = (int*)wp;                     wp += (size_t)nb * kBCap * 4;
    int* csr    = (int*)wp;

    // zero deg+cur+ovfcnt in one shot (contiguous; ws re-poisoned each call)
    hipMemsetAsync(deg, 0, (size_t)n_total * 4 + 6252 * 4 + 16, stream);

    xw_kernel<<<1024, 256, 0, stream>>>(features, preference, W_mlp, b_mlp,
                                        W_conv, xwb, n_total);

    const int egrid = (nE / 4 + 255) / 256;
    binhist_kernel<<<egrid, 256, 0, stream>>>(edge_index, edge_index + nE,
                                              deg, cur, bucket, ovfcnt, ovf, nE);

    const int nblk = (n_total + 1023) / 1024;  // 98 (<= 128 for scan_apply)
    scan_part<<<nblk, 256, 0, stream>>>(deg, off, part, n_total);
    scan_apply<<<nblk, 256, 0, stream>>>(part, off, n_total);

    bfill_kernel<<<nb, 256, 0, stream>>>(cur, bucket, off, csr);
    ovf_kernel<<<8, 256, 0, stream>>>(ovfcnt, ovf, off, csr);

    gather_kernel<<<(n_total + 3) / 4, 256, 0, stream>>>(
        (const uint4*)xwb, off, csr, (float4*)d_out, n_total);
}

// Round 13
// 271.668 us; speedup vs baseline: 1.2990x; 1.2990x over previous
//
#include <hip/hip_runtime.h>
#include <hip/hip_bf16.h>

// Problem constants (from reference): NU=NI=50000, DF=128, DL=64, E=1.2e6
constexpr int kNU = 50000;
constexpr int kDF = 128;
constexpr int kDL = 64;
constexpr int kEPB = 2048;             // edges per block in passA/passB

__device__ __forceinline__ float bf16hi_to_f(unsigned int u) {
    return __uint_as_float(u);
}

// ---------------------------------------------------------------------------
// xw_kernel: [MLP (rows >= NU) | preference] -> L2 normalize -> @W_conv
//            -> bf16 xw table.  (round-8 proven structure, unchanged)
// ---------------------------------------------------------------------------
__global__ __launch_bounds__(256) void xw_kernel(
    const float* __restrict__ features,    // [NI, 128]
    const float* __restrict__ preference,  // [NU, 64]
    const float* __restrict__ W_mlp,       // [64, 128] row-major
    const float* __restrict__ b_mlp,       // [64]
    const float* __restrict__ W_conv,      // [64, 64] row-major
    __hip_bfloat16* __restrict__ xwb,      // [n, 64] bf16
    int n_total)
{
    __shared__ float Wt[kDF * 65];         // Wt[k*65+l] = W_mlp[l][k]
    __shared__ float Wc[kDL * kDL];
    __shared__ float bs[kDL];
    __shared__ float frow[4][2][kDF];
    __shared__ float xls[4][2][kDL];

    const int tid = threadIdx.x;
    for (int idx = tid; idx < kDL * kDF; idx += 256) {
        int k = idx & (kDF - 1);
        int l = idx >> 7;
        Wt[k * 65 + l] = W_mlp[idx];
    }
    for (int idx = tid; idx < kDL * kDL; idx += 256) Wc[idx] = W_conv[idx];
    if (tid < kDL) bs[tid] = b_mlp[tid];
    __syncthreads();

    const int lane   = tid & 63;
    const int wid    = tid >> 6;
    const int wglob  = blockIdx.x * 4 + wid;
    const int nwaves = gridDim.x * 4;
    const int npairs = n_total >> 1;

    for (int pr = wglob; pr < npairs; pr += nwaves) {
        const int rA = 2 * pr, rB = rA + 1;
        float vA, vB;
        if (rA < kNU) {
            vA = preference[(size_t)rA * kDL + lane];
            vB = preference[(size_t)rB * kDL + lane];
        } else {
            const float* fA = features + (size_t)(rA - kNU) * kDF;
            const float* fB = fA + kDF;
            frow[wid][0][lane]      = fA[lane];
            frow[wid][0][lane + 64] = fA[lane + 64];
            frow[wid][1][lane]      = fB[lane];
            frow[wid][1][lane + 64] = fB[lane + 64];
            float a0 = bs[lane], a1 = 0.f, a2 = 0.f, a3 = 0.f;
            float c0 = bs[lane], c1 = 0.f, c2 = 0.f, c3 = 0.f;
            #pragma unroll
            for (int k = 0; k < kDF; k += 4) {
                const float4 fa = *reinterpret_cast<const float4*>(&frow[wid][0][k]);
                const float4 fb = *reinterpret_cast<const float4*>(&frow[wid][1][k]);
                const float w0 = Wt[(k)     * 65 + lane];
                const float w1 = Wt[(k + 1) * 65 + lane];
                const float w2 = Wt[(k + 2) * 65 + lane];
                const float w3 = Wt[(k + 3) * 65 + lane];
                a0 = fmaf(fa.x, w0, a0);  c0 = fmaf(fb.x, w0, c0);
                a1 = fmaf(fa.y, w1, a1);  c1 = fmaf(fb.y, w1, c1);
                a2 = fmaf(fa.z, w2, a2);  c2 = fmaf(fb.z, w2, c2);
                a3 = fmaf(fa.w, w3, a3);  c3 = fmaf(fb.w, w3, c3);
            }
            vA = (a0 + a1) + (a2 + a3);
            vB = (c0 + c1) + (c2 + c3);
        }
        float sA = vA * vA, sB = vB * vB;
        #pragma unroll
        for (int o = 32; o > 0; o >>= 1) {
            sA += __shfl_xor(sA, o);
            sB += __shfl_xor(sB, o);
        }
        const float xlA = vA / fmaxf(sqrtf(sA), 1e-12f);
        const float xlB = vB / fmaxf(sqrtf(sB), 1e-12f);
        xls[wid][0][lane] = xlA;
        xls[wid][1][lane] = xlB;

        float pA0 = 0.f, pA1 = 0.f, pA2 = 0.f, pA3 = 0.f;
        float pB0 = 0.f, pB1 = 0.f, pB2 = 0.f, pB3 = 0.f;
        #pragma unroll
        for (int l = 0; l < kDL; l += 4) {
            const float4 xA = *reinterpret_cast<const float4*>(&xls[wid][0][l]);
            const float4 xB = *reinterpret_cast<const float4*>(&xls[wid][1][l]);
            const float w0 = Wc[(l)     * kDL + lane];
            const float w1 = Wc[(l + 1) * kDL + lane];
            const float w2 = Wc[(l + 2) * kDL + lane];
            const float w3 = Wc[(l + 3) * kDL + lane];
            pA0 = fmaf(xA.x, w0, pA0);  pB0 = fmaf(xB.x, w0, pB0);
            pA1 = fmaf(xA.y, w1, pA1);  pB1 = fmaf(xB.y, w1, pB1);
            pA2 = fmaf(xA.z, w2, pA2);  pB2 = fmaf(xB.z, w2, pB2);
            pA3 = fmaf(xA.w, w3, pA3);  pB3 = fmaf(xB.w, w3, pB3);
        }
        xwb[(size_t)rA * kDL + lane] = __float2bfloat16((pA0 + pA1) + (pA2 + pA3));
        xwb[(size_t)rB * kDL + lane] = __float2bfloat16((pB0 + pB1) + (pB2 + pB3));
    }
}

// ---------------------------------------------------------------------------
// passA: per-block LDS histogram of bin = dst>>9; one global atomic per
// (block,bin).  No scattered global stores.
// ---------------------------------------------------------------------------
__global__ __launch_bounds__(256) void passA_kernel(
    const int* __restrict__ dst, int* __restrict__ bintot, int nE, int nbin)
{
    __shared__ int cnt[256];
    const int tid = threadIdx.x;
    cnt[tid] = 0;
    __syncthreads();
    const int base = blockIdx.x * kEPB;
    const int m = min(kEPB, nE - base);
    for (int k = tid; k < m; k += 256)
        atomicAdd(&cnt[dst[base + k] >> 9], 1);
    __syncthreads();
    if (tid < nbin && cnt[tid]) atomicAdd(&bintot[tid], cnt[tid]);
}

// ---------------------------------------------------------------------------
// seed: single block; exclusive scan of bintot[nbin] -> partbase[0..nbin],
// seed gcur[b] = partbase[b].
// ---------------------------------------------------------------------------
__global__ __launch_bounds__(256) void seed_kernel(
    const int* __restrict__ bintot, int* __restrict__ partbase,
    int* __restrict__ gcur, int nbin)
{
    __shared__ int wq[4];
    const int tid = threadIdx.x, lane = tid & 63, w = tid >> 6;
    const int v = (tid < nbin) ? bintot[tid] : 0;
    int s = v;
    #pragma unroll
    for (int d = 1; d < 64; d <<= 1) {
        int u = __shfl_up(s, d);
        if (lane >= d) s += u;
    }
    if (lane == 63) wq[w] = s;
    __syncthreads();
    int add = 0;
    for (int j = 0; j < w; ++j) add += wq[j];
    const int excl = s + add - v;
    if (tid < nbin) { partbase[tid] = excl; gcur[tid] = excl; }
    else if (tid == nbin) partbase[nbin] = excl;
}

// ---------------------------------------------------------------------------
// passB: per-block LDS count -> scan -> bin-ordered reorder -> COALESCED
// flush to part[].  Packed entry (src<<9)|(dst&511) fits 26 bits.
// Consecutive threads write consecutive addresses of each (block,bin)
// segment -> ~1x write amplification.
// ---------------------------------------------------------------------------
__global__ __launch_bounds__(256) void passB_kernel(
    const int* __restrict__ src, const int* __restrict__ dst,
    int* __restrict__ gcur, unsigned* __restrict__ part, int nE, int nbin)
{
    __shared__ int cnt[256];               // counts, then reused as cursor
    __shared__ int scn[256];               // exclusive local scan
    __shared__ int gbase[256];
    __shared__ int wq[4];
    __shared__ unsigned buf[kEPB];
    __shared__ unsigned char binq[kEPB];

    const int tid = threadIdx.x;
    cnt[tid] = 0;
    __syncthreads();
    const int base = blockIdx.x * kEPB;
    const int m = min(kEPB, nE - base);
    // loop 1: count bins
    for (int k = tid; k < m; k += 256)
        atomicAdd(&cnt[dst[base + k] >> 9], 1);
    __syncthreads();
    // exclusive scan of cnt[256]
    const int v = cnt[tid];
    int s = v;
    const int lane = tid & 63, w = tid >> 6;
    #pragma unroll
    for (int d = 1; d < 64; d <<= 1) {
        int u = __shfl_up(s, d);
        if (lane >= d) s += u;
    }
    if (lane == 63) wq[w] = s;
    __syncthreads();
    int add = 0;
    for (int j = 0; j < w; ++j) add += wq[j];
    const int excl = s + add - v;
    scn[tid] = excl;
    // reserve global segment: one atomic per nonempty (block,bin)
    gbase[tid] = (tid < nbin && v) ? atomicAdd(&gcur[tid], v) : 0;
    __syncthreads();
    cnt[tid] = excl;                       // cursor
    __syncthreads();
    // loop 2: reorder into LDS (re-read edges; coalesced, L2-hot)
    for (int k = tid; k < m; k += 256) {
        const int d = dst[base + k];
        const int ssrc = src[base + k];
        const int b = d >> 9;
        const int p = atomicAdd(&cnt[b], 1);
        buf[p]  = ((unsigned)ssrc << 9) | (unsigned)(d & 511);
        binq[p] = (unsigned char)b;
    }
    __syncthreads();
    // coalesced flush
    for (int q = tid; q < m; q += 256) {
        const int b = binq[q];
        part[gbase[b] + (q - scn[b])] = buf[q];
    }
}

// ---------------------------------------------------------------------------
// passC: one block per partition (512 dst rows).  LDS deg-count -> scan ->
// off row-ends (coalesced) -> csr placement confined to the partition's
// contiguous span (single block owns it -> ~1x write-back).
// ---------------------------------------------------------------------------
__global__ __launch_bounds__(256) void passC_kernel(
    const unsigned* __restrict__ part, const int* __restrict__ partbase,
    int* __restrict__ off, int* __restrict__ csr, int n_total)
{
    __shared__ int degl[512];              // counts, then cursor
    __shared__ int startl[512];
    __shared__ int wq[4];
    __shared__ unsigned stash[8192];

    const int b  = blockIdx.x;
    const int p0 = partbase[b], p1 = partbase[b + 1];
    const int m  = p1 - p0;
    const int row0  = b << 9;
    const int nrows = min(512, n_total - row0);
    const int tid = threadIdx.x;

    for (int i = tid; i < 512; i += 256) degl[i] = 0;
    __syncthreads();
    const bool useStash = (m <= 8192);
    for (int q = tid; q < m; q += 256) {
        const unsigned pk = part[p0 + q];
        if (useStash) stash[q] = pk;
        atomicAdd(&degl[pk & 511u], 1);
    }
    __syncthreads();
    // scan 512 (2 elems/thread)
    const int a0 = degl[2 * tid], a1 = degl[2 * tid + 1];
    const int t = a0 + a1;
    int s = t;
    const int lane = tid & 63, w = tid >> 6;
    #pragma unroll
    for (int d = 1; d < 64; d <<= 1) {
        int u = __shfl_up(s, d);
        if (lane >= d) s += u;
    }
    if (lane == 63) wq[w] = s;
    __syncthreads();
    int add = 0;
    for (int j = 0; j < w; ++j) add += wq[j];
    const int excl = s + add - t;
    startl[2 * tid]     = excl;
    startl[2 * tid + 1] = excl + a0;
    __syncthreads();
    // row ends -> off (coalesced)
    for (int r = tid; r < nrows; r += 256)
        off[row0 + r] = p0 + startl[r] + degl[r];
    __syncthreads();
    // cursor init
    for (int r = tid; r < 512; r += 256) degl[r] = startl[r];
    __syncthreads();
    // place into the partition's contiguous csr span
    for (int q = tid; q < m; q += 256) {
        const unsigned pk = useStash ? stash[q] : part[p0 + q];
        const int r = (int)(pk & 511u);
        const int p = atomicAdd(&degl[r], 1);
        csr[p0 + p] = (int)(pk >> 9);
    }
}

// ---------------------------------------------------------------------------
// gather (round-8 proven, unchanged): one wave per dst row; 8 groups x 8
// lanes; CSR row preloaded coalesced + shfl redistribute; bf16 rows as
// uint4; fused leaky; float4 stores.
// ---------------------------------------------------------------------------
__global__ __launch_bounds__(256) void gather_kernel(
    const uint4* __restrict__ xwb4,
    const int* __restrict__ off,           // end offsets per row
    const int* __restrict__ csr,
    float4* __restrict__ out4, int n)
{
    const int r = blockIdx.x * 4 + (threadIdx.x >> 6);
    if (r >= n) return;
    const int lane = threadIdx.x & 63;
    const int g = lane >> 3;
    const int c = lane & 7;
    const int e0  = r ? off[r - 1] : 0;
    const int deg = off[r] - e0;

    const int s_all = (lane < deg) ? csr[e0 + lane] : 0;

    float acc[8];
    #pragma unroll
    for (int j = 0; j < 8; ++j) acc[j] = 0.f;

    for (int base = 0; base < deg; base += 8) {
        const int idx = base + g;
        int s = (idx < 64) ? __shfl(s_all, idx)
                           : ((idx < deg) ? csr[e0 + idx] : 0);
        if (idx < deg) {
            const uint4 v = xwb4[(size_t)s * 8 + c];
            acc[0] += bf16hi_to_f(v.x << 16);
            acc[1] += bf16hi_to_f(v.x & 0xffff0000u);
            acc[2] += bf16hi_to_f(v.y << 16);
            acc[3] += bf16hi_to_f(v.y & 0xffff0000u);
            acc[4] += bf16hi_to_f(v.z << 16);
            acc[5] += bf16hi_to_f(v.z & 0xffff0000u);
            acc[6] += bf16hi_to_f(v.w << 16);
            acc[7] += bf16hi_to_f(v.w & 0xffff0000u);
        }
    }
    #pragma unroll
    for (int j = 0; j < 8; ++j) {
        acc[j] += __shfl_xor(acc[j], 8);
        acc[j] += __shfl_xor(acc[j], 16);
        acc[j] += __shfl_xor(acc[j], 32);
    }
    if (g == 0) {
        #pragma unroll
        for (int j = 0; j < 8; ++j)
            acc[j] = acc[j] >= 0.f ? acc[j] : 0.01f * acc[j];
        const float4 o0 = make_float4(acc[0], acc[1], acc[2], acc[3]);
        const float4 o1 = make_float4(acc[4], acc[5], acc[6], acc[7]);
        out4[(size_t)r * 16 + c * 2]     = o0;
        out4[(size_t)r * 16 + c * 2 + 1] = o1;
    }
}

extern "C" void kernel_launch(void* const* d_in, const int* in_sizes, int n_in,
                              void* d_out, int out_size, void* d_ws, size_t ws_size,
                              hipStream_t stream) {
    // inputs: 0=id_embedding (UNUSED), 1=features, 2=preference,
    //         3=W_mlp, 4=b_mlp, 5=W_conv, 6=edge_index
    const float* features   = (const float*)d_in[1];
    const float* preference = (const float*)d_in[2];
    const float* W_mlp      = (const float*)d_in[3];
    const float* b_mlp      = (const float*)d_in[4];
    const float* W_conv     = (const float*)d_in[5];
    const int*   edge_index = (const int*)d_in[6];

    const int nE      = in_sizes[6] / 2;           // 1,200,000
    const int n_total = out_size / kDL;            // 100,000
    const int nbin    = (n_total + 511) >> 9;      // 196 partitions (<=256)

    // ws layout (16B-aligned segments), ~23 MB total:
    //   xwb      : n_total*64 bf16 = 12,800,000 B
    //   off      : (n_total+4) int =    400,016 B
    //   bintot   : 256 int         =      1,024 B   (memset)
    //   partbase : 260 int         =      1,040 B
    //   gcur     : 256 int         =      1,024 B
    //   part     : nE u32          =  4,800,000 B
    //   csr      : nE int          =  4,800,000 B
    char* wp = (char*)d_ws;
    __hip_bfloat16* xwb = (__hip_bfloat16*)wp;  wp += (size_t)n_total * kDL * 2;
    int* off      = (int*)wp;                   wp += (size_t)(n_total + 4) * 4;
    int* bintot   = (int*)wp;                   wp += 1024;
    int* partbase = (int*)wp;                   wp += 1040;
    int* gcur     = (int*)wp;                   wp += 1024;
    unsigned* part = (unsigned*)wp;             wp += (size_t)nE * 4;
    int* csr      = (int*)wp;

    hipMemsetAsync(bintot, 0, 1024, stream);    // tiny; ws re-poisoned each call

    xw_kernel<<<1024, 256, 0, stream>>>(features, preference, W_mlp, b_mlp,
                                        W_conv, xwb, n_total);

    const int ngrid = (nE + kEPB - 1) / kEPB;   // 586 blocks
    passA_kernel<<<ngrid, 256, 0, stream>>>(edge_index + nE, bintot, nE, nbin);
    seed_kernel<<<1, 256, 0, stream>>>(bintot, partbase, gcur, nbin);
    passB_kernel<<<ngrid, 256, 0, stream>>>(edge_index, edge_index + nE,
                                            gcur, part, nE, nbin);
    passC_kernel<<<nbin, 256, 0, stream>>>(part, partbase, off, csr, n_total);

    gather_kernel<<<(n_total + 3) / 4, 256, 0, stream>>>(
        (const uint4*)xwb, off, csr, (float4*)d_out, n_total);
}